// Round 4
// baseline (227.062 us; speedup 1.0000x reference)
//
#include <hip/hip_runtime.h>
#include <hip/hip_bf16.h>
#include <stdint.h>

#define HIDDEN  1024
#define FFN_DIM 2048
#define NEXP    8
#define NTOK    2048          // B*S
#define MAXROWS 5120          // sum of 128-padded per-expert counts

typedef short bf16x8 __attribute__((ext_vector_type(8)));
typedef float f32x4  __attribute__((ext_vector_type(4)));

// ---------------- ws layout (bytes) ----------------
static const size_t OFF_CNT  = 0;                         // 8 ints
static const size_t OFF_BASE = 64;                        // 9 ints
static const size_t OFF_TOK  = 128;                       // 8*2048 ints
static const size_t OFF_WGT  = OFF_TOK + (size_t)NEXP*NTOK*4;
static const size_t OFF_XBF  = 131328;                    // 256-aligned
static const size_t XBF_B    = (size_t)NTOK*HIDDEN*2;
static const size_t OFF_H    = OFF_XBF + XBF_B;
static const size_t H_B      = (size_t)MAXROWS*FFN_DIM*2;
static const size_t WS_NEED  = OFF_H + H_B;               // ~25 MB

__device__ __forceinline__ unsigned short f2bf(float f) {
  union { float f; unsigned u; } a; a.f = f;
  unsigned r = a.u + 0x7fff + ((a.u >> 16) & 1);          // RTN-even
  return (unsigned short)(r >> 16);
}

// 8 fp32 -> 8 bf16 packed in a uint4 (memory order preserved)
__device__ __forceinline__ uint4 cvt8(float4 a, float4 b) {
  uint4 r;
  asm("v_cvt_pk_bf16_f32 %0, %1, %2" : "=v"(r.x) : "v"(a.x), "v"(a.y));
  asm("v_cvt_pk_bf16_f32 %0, %1, %2" : "=v"(r.y) : "v"(a.z), "v"(a.w));
  asm("v_cvt_pk_bf16_f32 %0, %1, %2" : "=v"(r.z) : "v"(b.x), "v"(b.y));
  asm("v_cvt_pk_bf16_f32 %0, %1, %2" : "=v"(r.w) : "v"(b.z), "v"(b.w));
  return r;
}

__device__ __forceinline__ void ld_g2l16(const void* gsrc, void* ldst) {
  __builtin_amdgcn_global_load_lds(
      (const __attribute__((address_space(1))) unsigned int*)gsrc,
      (__attribute__((address_space(3))) unsigned int*)ldst, 16, 0, 0);
}

// ---------------- Router: fp32-exact logits, top-2, renorm weights, expert bins ----------------
__global__ __launch_bounds__(256) void router_kernel(
    const float* __restrict__ x, const float* __restrict__ gw,
    float* __restrict__ logits, int* __restrict__ cnt,
    int* __restrict__ tok, float* __restrict__ wgt)
{
  const int t   = blockIdx.x;
  const int tid = threadIdx.x;
  float4 xv = ((const float4*)(x + (size_t)t * HIDDEN))[tid];
  float p[NEXP];
#pragma unroll
  for (int e = 0; e < NEXP; ++e) {
    float4 gv = ((const float4*)(gw + (size_t)e * HIDDEN))[tid];
    p[e] = xv.x * gv.x + xv.y * gv.y + xv.z * gv.z + xv.w * gv.w;
  }
#pragma unroll
  for (int e = 0; e < NEXP; ++e) {
#pragma unroll
    for (int off = 32; off > 0; off >>= 1)
      p[e] += __shfl_down(p[e], off, 64);
  }
  __shared__ float red[4][NEXP];
  const int wv = tid >> 6, ln = tid & 63;
  if (ln == 0) {
#pragma unroll
    for (int e = 0; e < NEXP; ++e) red[wv][e] = p[e];
  }
  __syncthreads();
  if (tid == 0) {
    float l[NEXP];
#pragma unroll
    for (int e = 0; e < NEXP; ++e) {
      l[e] = red[0][e] + red[1][e] + red[2][e] + red[3][e];
      logits[(size_t)t * NEXP + e] = l[e];
    }
    int i0 = 0;
#pragma unroll
    for (int e = 1; e < NEXP; ++e) if (l[e] > l[i0]) i0 = e;
    int i1 = (i0 == 0) ? 1 : 0;
#pragma unroll
    for (int e = 0; e < NEXP; ++e) if (e != i0 && l[e] > l[i1]) i1 = e;
    float w0 = 1.f / (1.f + expf(l[i1] - l[i0]));
    float w1 = 1.f - w0;
    int s0 = atomicAdd(&cnt[i0], 1);
    tok[i0 * NTOK + s0] = t;  wgt[i0 * NTOK + s0] = w0;
    int s1 = atomicAdd(&cnt[i1], 1);
    tok[i1 * NTOK + s1] = t;  wgt[i1 * NTOK + s1] = w1;
  }
}

// ---------------- 128-padded per-expert row bases ----------------
__global__ void prefix_kernel(const int* __restrict__ cnt, int* __restrict__ base) {
  if (threadIdx.x == 0 && blockIdx.x == 0) {
    int b = 0;
#pragma unroll
    for (int e = 0; e < NEXP; ++e) { base[e] = b; b += ((cnt[e] + 127) >> 7) << 7; }
    base[NEXP] = b;
  }
}

// ---------------- fp32 -> bf16 conversion (x only) ----------------
__global__ __launch_bounds__(256) void cvt_kernel(
    const float* __restrict__ src, unsigned short* __restrict__ dst, int n4)
{
  int i = blockIdx.x * blockDim.x + threadIdx.x;
  const int stride = gridDim.x * blockDim.x;
  for (; i < n4; i += stride) {
    float4 v = ((const float4*)src)[i];
    ushort4 o;
    o.x = f2bf(v.x); o.y = f2bf(v.y); o.z = f2bf(v.z); o.w = f2bf(v.w);
    ((ushort4*)dst)[i] = o;
  }
}

// ---------------- GEMM1: H = silu(X W1^T) * (X W3^T), fp32 weights cvt'd during staging ----------
// LDS layout: [128 rows][8 units of 16B]; unit u_l of row r holds global unit (u_l ^ (r&7)).
// X staged via linear global_load_lds with pre-swizzled global source; W1/W3 reg-staged
// (global fp32 -> cvt_pk -> ds_write_b128 at the linear slot whose source unit is pre-swizzled).
__global__ __launch_bounds__(512, 4) void gemm1_kernel(
    const unsigned short* __restrict__ xbf,   // [NTOK][HIDDEN] bf16
    const float* __restrict__ w1f,            // [E][FFN][HIDDEN] fp32
    const float* __restrict__ w3f,
    const int* __restrict__ cnt, const int* __restrict__ base,
    const int* __restrict__ tok,
    unsigned short* __restrict__ H)           // [MAXROWS][FFN] bf16
{
  // XCD-grouped decomposition: expert = bid%8 (one expert per XCD), mt fastest within XCD.
  const int bid  = blockIdx.x;
  const int e    = bid & 7;
  const int slot = bid >> 3;            // 0..255
  const int mt   = slot & 15;
  const int nt   = slot >> 4;
  const int n = cnt[e];
  if (mt * 128 >= n) return;
  const int t = threadIdx.x;
  const int w = t >> 6, l = t & 63;

  __shared__ unsigned short Xs [128 * 64];
  __shared__ unsigned short W1s[128 * 64];
  __shared__ unsigned short W3s[128 * 64];
  __shared__ int stok[128];

  if (t < 128) {
    int idx = mt * 128 + t;
    stok[t] = tok[e * NTOK + min(idx, n - 1)];   // pad rows: duplicate last (masked later)
  }
  __syncthreads();

  const int r0 = t >> 3;                             // staged row (and r0+64)
  const size_t tok0 = (size_t)stok[r0];
  const size_t tok1 = (size_t)stok[64 + r0];
  const int kp = (((t & 7) ^ ((t >> 3) & 7)) << 3);  // pre-swizzled source unit offset (elems)

  const float* w1e = w1f + (size_t)e * FFN_DIM * HIDDEN + (size_t)(nt * 128) * HIDDEN;
  const float* w3e = w3f + (size_t)e * FFN_DIM * HIDDEN + (size_t)(nt * 128) * HIDDEN;
  const float* w1p0 = w1e + (size_t)r0        * HIDDEN + kp;
  const float* w1p1 = w1e + (size_t)(64 + r0) * HIDDEN + kp;
  const float* w3p0 = w3e + (size_t)r0        * HIDDEN + kp;
  const float* w3p1 = w3e + (size_t)(64 + r0) * HIDDEN + kp;

  // LDS write slots (linear: thread t covers bytes [t*16, t*16+16) of each 8KB half)
  uint4* lw1a = (uint4*)((char*)W1s + t * 16);
  uint4* lw1b = (uint4*)((char*)W1s + 8192 + t * 16);
  uint4* lw3a = (uint4*)((char*)W3s + t * 16);
  uint4* lw3b = (uint4*)((char*)W3s + 8192 + t * 16);
  char* ldsX = (char*)Xs + w * 1024;    // wave-uniform base for global_load_lds

  f32x4 acc1[4][2], acc3[4][2];
#pragma unroll
  for (int i = 0; i < 4; ++i)
#pragma unroll
    for (int j = 0; j < 2; ++j) { acc1[i][j] = (f32x4)0.f; acc3[i][j] = (f32x4)0.f; }

  const int Moff = (w & 1) * 64;
  const int Noff = (w >> 1) * 32;
  const int lr = l & 15;
  const int lg = l >> 4;

  for (int kb = 0; kb < HIDDEN / 64; ++kb) {
    __syncthreads();                    // previous compute done with LDS
    const int kofs = kb * 64 + kp;
    ld_g2l16(xbf + tok0 * HIDDEN + kofs, ldsX);          // X in flight under W staging
    ld_g2l16(xbf + tok1 * HIDDEN + kofs, ldsX + 8192);
    {
      const int ko = kb * 64;
      float4 a0 = *(const float4*)(w1p0 + ko);
      float4 a1 = *(const float4*)(w1p0 + ko + 4);
      float4 a2 = *(const float4*)(w1p1 + ko);
      float4 a3 = *(const float4*)(w1p1 + ko + 4);
      float4 b0 = *(const float4*)(w3p0 + ko);
      float4 b1 = *(const float4*)(w3p0 + ko + 4);
      float4 b2 = *(const float4*)(w3p1 + ko);
      float4 b3 = *(const float4*)(w3p1 + ko + 4);
      *lw1a = cvt8(a0, a1);
      *lw1b = cvt8(a2, a3);
      *lw3a = cvt8(b0, b1);
      *lw3b = cvt8(b2, b3);
    }
    __syncthreads();                    // staging complete (vm+lgkm drained)
#pragma unroll
    for (int s = 0; s < 2; ++s) {
      const int ug = 4 * s + lg;        // global k-unit this fragment wants
      bf16x8 a[4], b1v[2], b3v[2];
#pragma unroll
      for (int mi = 0; mi < 4; ++mi) {
        const int R = Moff + mi * 16 + lr;
        a[mi] = *(const bf16x8*)&Xs[R * 64 + ((ug ^ (lr & 7)) << 3)];
      }
#pragma unroll
      for (int ni = 0; ni < 2; ++ni) {
        const int R = Noff + ni * 16 + lr;
        b1v[ni] = *(const bf16x8*)&W1s[R * 64 + ((ug ^ (lr & 7)) << 3)];
        b3v[ni] = *(const bf16x8*)&W3s[R * 64 + ((ug ^ (lr & 7)) << 3)];
      }
#pragma unroll
      for (int mi = 0; mi < 4; ++mi)
#pragma unroll
        for (int ni = 0; ni < 2; ++ni) {
          acc1[mi][ni] = __builtin_amdgcn_mfma_f32_16x16x32_bf16(a[mi], b1v[ni], acc1[mi][ni], 0, 0, 0);
          acc3[mi][ni] = __builtin_amdgcn_mfma_f32_16x16x32_bf16(a[mi], b3v[ni], acc3[mi][ni], 0, 0, 0);
        }
    }
  }

  const size_t rbase = (size_t)base[e] + (size_t)mt * 128;
#pragma unroll
  for (int mi = 0; mi < 4; ++mi)
#pragma unroll
    for (int ni = 0; ni < 2; ++ni)
#pragma unroll
      for (int j = 0; j < 4; ++j) {
        int row = Moff + mi * 16 + lg * 4 + j;
        int col = nt * 128 + Noff + ni * 16 + lr;
        float s1 = acc1[mi][ni][j], s3 = acc3[mi][ni][j];
        float h = (s1 / (1.f + __expf(-s1))) * s3;      // silu(s1)*s3
        H[(rbase + row) * FFN_DIM + col] = f2bf(h);
      }
}

// ---------------- GEMM2: Y = H W2^T (fp32 W2 cvt'd during staging), weighted atomicAdd ----------
__global__ __launch_bounds__(512, 4) void gemm2_kernel(
    const unsigned short* __restrict__ H,
    const float* __restrict__ w2f,            // [E][HIDDEN][FFN] fp32
    const int* __restrict__ cnt, const int* __restrict__ base,
    const int* __restrict__ tok, const float* __restrict__ wgt,
    float* __restrict__ out)
{
  const int bid  = blockIdx.x;
  const int e    = bid & 7;
  const int slot = bid >> 3;            // 0..127
  const int mt   = slot & 15;
  const int nt   = slot >> 4;           // 0..7
  const int n = cnt[e];
  if (mt * 128 >= n) return;
  const int t = threadIdx.x;
  const int w = t >> 6, l = t & 63;

  __shared__ unsigned short Hs[128 * 64];
  __shared__ unsigned short Ws[128 * 64];
  __shared__ int   stok[128];
  __shared__ float swgt[128];

  if (t < 128) {
    int idx = mt * 128 + t;
    int ok = idx < n;
    stok[t] = ok ? tok[e * NTOK + idx] : -1;
    swgt[t] = ok ? wgt[e * NTOK + idx] : 0.f;
  }

  const int r0 = t >> 3;
  const int kp = (((t & 7) ^ ((t >> 3) & 7)) << 3);
  const unsigned short* He = H + (size_t)(base[e] + mt * 128) * FFN_DIM;
  const float* w2e  = w2f + (size_t)e * HIDDEN * FFN_DIM + (size_t)(nt * 128) * FFN_DIM;
  const float* w2p0 = w2e + (size_t)r0        * FFN_DIM + kp;
  const float* w2p1 = w2e + (size_t)(64 + r0) * FFN_DIM + kp;

  uint4* lwa = (uint4*)((char*)Ws + t * 16);
  uint4* lwb = (uint4*)((char*)Ws + 8192 + t * 16);
  char* ldsH = (char*)Hs + w * 1024;

  f32x4 acc[4][2];
#pragma unroll
  for (int i = 0; i < 4; ++i)
#pragma unroll
    for (int j = 0; j < 2; ++j) acc[i][j] = (f32x4)0.f;

  const int Moff = (w & 1) * 64;
  const int Noff = (w >> 1) * 32;
  const int lr = l & 15;
  const int lg = l >> 4;

  for (int kb = 0; kb < FFN_DIM / 64; ++kb) {
    __syncthreads();
    const int kofs = kb * 64 + kp;
    ld_g2l16(He + (size_t)r0 * FFN_DIM + kofs,        ldsH);
    ld_g2l16(He + (size_t)(64 + r0) * FFN_DIM + kofs, ldsH + 8192);
    {
      const int ko = kb * 64;
      float4 a0 = *(const float4*)(w2p0 + ko);
      float4 a1 = *(const float4*)(w2p0 + ko + 4);
      float4 a2 = *(const float4*)(w2p1 + ko);
      float4 a3 = *(const float4*)(w2p1 + ko + 4);
      *lwa = cvt8(a0, a1);
      *lwb = cvt8(a2, a3);
    }
    __syncthreads();
#pragma unroll
    for (int s = 0; s < 2; ++s) {
      const int ug = 4 * s + lg;
      bf16x8 a[4], b[2];
#pragma unroll
      for (int mi = 0; mi < 4; ++mi) {
        const int R = Moff + mi * 16 + lr;
        a[mi] = *(const bf16x8*)&Hs[R * 64 + ((ug ^ (lr & 7)) << 3)];
      }
#pragma unroll
      for (int ni = 0; ni < 2; ++ni) {
        const int R = Noff + ni * 16 + lr;
        b[ni] = *(const bf16x8*)&Ws[R * 64 + ((ug ^ (lr & 7)) << 3)];
      }
#pragma unroll
      for (int mi = 0; mi < 4; ++mi)
#pragma unroll
        for (int ni = 0; ni < 2; ++ni)
          acc[mi][ni] = __builtin_amdgcn_mfma_f32_16x16x32_bf16(a[mi], b[ni], acc[mi][ni], 0, 0, 0);
    }
  }

#pragma unroll
  for (int mi = 0; mi < 4; ++mi)
#pragma unroll
    for (int ni = 0; ni < 2; ++ni)
#pragma unroll
      for (int j = 0; j < 4; ++j) {
        int row = Moff + mi * 16 + lg * 4 + j;
        int tk = stok[row];
        if (tk >= 0) {
          int col = nt * 128 + Noff + ni * 16 + lr;
          atomicAdd(&out[(size_t)tk * HIDDEN + col], swgt[row] * acc[mi][ni][j]);
        }
      }
}

// ================= fp32 fallback path (used only if ws too small) =================
#define TT 12
#define FC 256
#define NCHUNK (FFN_DIM / FC)

__global__ __launch_bounds__(256) void moe_ffn_kernel(
    const float* __restrict__ x,
    const float* __restrict__ w1, const float* __restrict__ w2,
    const float* __restrict__ w3,
    const int* __restrict__ cnt, const int* __restrict__ tok,
    const float* __restrict__ wgt, float* __restrict__ out)
{
  const int e  = blockIdx.y;
  const int n  = cnt[e];
  const int ts = blockIdx.x * TT;
  if (ts >= n) return;
  const int tid = threadIdx.x;

  __shared__ float xs[TT * HIDDEN];
  __shared__ float hc[TT * FC];
  __shared__ int   stok[TT];
  __shared__ float swgt[TT];

  if (tid < TT) {
    int idx = ts + tid;
    int tk  = (idx < n) ? tok[e * NTOK + idx] : -1;
    stok[tid] = tk;
    swgt[tid] = (idx < n) ? wgt[e * NTOK + idx] : 0.f;
  }
  __syncthreads();
#pragma unroll
  for (int i = 0; i < TT; ++i) {
    int tk = stok[i];
    float4 v = make_float4(0.f, 0.f, 0.f, 0.f);
    if (tk >= 0) v = ((const float4*)(x + (size_t)tk * HIDDEN))[tid];
    ((float4*)(xs + i * HIDDEN))[tid] = v;
  }
  __syncthreads();

  const float* w1e = w1 + (size_t)e * FFN_DIM * HIDDEN;
  const float* w3e = w3 + (size_t)e * FFN_DIM * HIDDEN;
  const float* w2e = w2 + (size_t)e * HIDDEN * FFN_DIM;

  float yacc[4][TT];
#pragma unroll
  for (int j = 0; j < 4; ++j)
#pragma unroll
    for (int t = 0; t < TT; ++t) yacc[j][t] = 0.f;

  for (int c = 0; c < NCHUNK; ++c) {
    const int f = c * FC + tid;
    const float4* r1 = (const float4*)(w1e + (size_t)f * HIDDEN);
    const float4* r3 = (const float4*)(w3e + (size_t)f * HIDDEN);
    float a1[TT], a3[TT];
#pragma unroll
    for (int t = 0; t < TT; ++t) { a1[t] = 0.f; a3[t] = 0.f; }
    for (int k = 0; k < HIDDEN / 4; ++k) {
      float4 v1 = r1[k];
      float4 v3 = r3[k];
#pragma unroll
      for (int t = 0; t < TT; ++t) {
        float4 xv = *(const float4*)(xs + t * HIDDEN + 4 * k);
        a1[t] += xv.x * v1.x + xv.y * v1.y + xv.z * v1.z + xv.w * v1.w;
        a3[t] += xv.x * v3.x + xv.y * v3.y + xv.z * v3.z + xv.w * v3.w;
      }
    }
    __syncthreads();
#pragma unroll
    for (int t = 0; t < TT; ++t) {
      float g  = a1[t];
      float sg = g / (1.f + __expf(-g));
      hc[t * FC + tid] = sg * a3[t];
    }
    __syncthreads();
    const float4* r20 = (const float4*)(w2e + (size_t)(tid      ) * FFN_DIM + c * FC);
    const float4* r21 = (const float4*)(w2e + (size_t)(tid + 256) * FFN_DIM + c * FC);
    const float4* r22 = (const float4*)(w2e + (size_t)(tid + 512) * FFN_DIM + c * FC);
    const float4* r23 = (const float4*)(w2e + (size_t)(tid + 768) * FFN_DIM + c * FC);
    for (int k = 0; k < FC / 4; ++k) {
      float4 wv0 = r20[k], wv1 = r21[k], wv2 = r22[k], wv3 = r23[k];
#pragma unroll
      for (int t = 0; t < TT; ++t) {
        float4 hv = *(const float4*)(hc + t * FC + 4 * k);
        yacc[0][t] += hv.x * wv0.x + hv.y * wv0.y + hv.z * wv0.z + hv.w * wv0.w;
        yacc[1][t] += hv.x * wv1.x + hv.y * wv1.y + hv.z * wv1.z + hv.w * wv1.w;
        yacc[2][t] += hv.x * wv2.x + hv.y * wv2.y + hv.z * wv2.z + hv.w * wv2.w;
        yacc[3][t] += hv.x * wv3.x + hv.y * wv3.y + hv.z * wv3.z + hv.w * wv3.w;
      }
    }
  }

#pragma unroll
  for (int t = 0; t < TT; ++t) {
    int tk = stok[t];
    if (tk < 0) continue;
    float wt = swgt[t];
    float* orow = out + (size_t)tk * HIDDEN;
    atomicAdd(orow + tid,       wt * yacc[0][t]);
    atomicAdd(orow + tid + 256, wt * yacc[1][t]);
    atomicAdd(orow + tid + 512, wt * yacc[2][t]);
    atomicAdd(orow + tid + 768, wt * yacc[3][t]);
  }
}

extern "C" void kernel_launch(void* const* d_in, const int* in_sizes, int n_in,
                              void* d_out, int out_size, void* d_ws, size_t ws_size,
                              hipStream_t stream) {
  const float* x  = (const float*)d_in[0];
  const float* gw = (const float*)d_in[1];
  const float* w1 = (const float*)d_in[2];
  const float* w2 = (const float*)d_in[3];
  const float* w3 = (const float*)d_in[4];
  float* out    = (float*)d_out;
  float* logits = out + (size_t)NTOK * HIDDEN;

  char* ws = (char*)d_ws;
  int*   cnt  = (int*)(ws + OFF_CNT);
  int*   base = (int*)(ws + OFF_BASE);
  int*   tokp = (int*)(ws + OFF_TOK);
  float* wgtp = (float*)(ws + OFF_WGT);

  hipMemsetAsync(out, 0, (size_t)NTOK * HIDDEN * sizeof(float), stream);
  hipMemsetAsync(cnt, 0, NEXP * sizeof(int), stream);

  router_kernel<<<NTOK, 256, 0, stream>>>(x, gw, logits, cnt, tokp, wgtp);

  if (ws_size >= WS_NEED) {
    unsigned short* xbf  = (unsigned short*)(ws + OFF_XBF);
    unsigned short* Hbuf = (unsigned short*)(ws + OFF_H);

    cvt_kernel<<<512, 256, 0, stream>>>(x, xbf, (int)(NTOK * HIDDEN / 4));
    prefix_kernel<<<1, 64, 0, stream>>>(cnt, base);

    gemm1_kernel<<<NEXP * 16 * 16, 512, 0, stream>>>(xbf, w1, w3, cnt, base, tokp, Hbuf);
    gemm2_kernel<<<NEXP * 16 * 8, 512, 0, stream>>>(Hbuf, w2, cnt, base, tokp, wgtp, out);
  } else {
    dim3 grid((NTOK + TT - 1) / TT, NEXP);
    moe_ffn_kernel<<<grid, 256, 0, stream>>>(x, w1, w2, w3, cnt, tokp, wgtp, out);
  }
}

// Round 5
// 217.481 us; speedup vs baseline: 1.0441x; 1.0441x over previous
//
#include <hip/hip_runtime.h>
#include <hip/hip_bf16.h>
#include <stdint.h>

#define HIDDEN  1024
#define FFN_DIM 2048
#define NEXP    8
#define NTOK    2048          // B*S
#define MAXROWS 5120          // sum of 64-padded per-expert counts <= 4096 + 8*63

typedef short bf16x8 __attribute__((ext_vector_type(8)));
typedef float f32x4  __attribute__((ext_vector_type(4)));

// ---------------- ws layout (bytes) ----------------
static const size_t OFF_CNT  = 0;                         // 8 ints
static const size_t OFF_BASE = 64;                        // 9 ints
static const size_t OFF_TOK  = 128;                       // 8*2048 ints
static const size_t OFF_WGT  = OFF_TOK + (size_t)NEXP*NTOK*4;
static const size_t OFF_XBF  = 131328;                    // 256-aligned
static const size_t XBF_B    = (size_t)NTOK*HIDDEN*2;
static const size_t OFF_H    = OFF_XBF + XBF_B;
static const size_t H_B      = (size_t)MAXROWS*FFN_DIM*2;
static const size_t WS_NEED  = OFF_H + H_B;               // ~25 MB

__device__ __forceinline__ unsigned short f2bf(float f) {
  union { float f; unsigned u; } a; a.f = f;
  unsigned r = a.u + 0x7fff + ((a.u >> 16) & 1);          // RTN-even
  return (unsigned short)(r >> 16);
}

// 8 fp32 -> 8 bf16 packed in a uint4 (memory order preserved)
__device__ __forceinline__ uint4 cvt8(float4 a, float4 b) {
  uint4 r;
  asm("v_cvt_pk_bf16_f32 %0, %1, %2" : "=v"(r.x) : "v"(a.x), "v"(a.y));
  asm("v_cvt_pk_bf16_f32 %0, %1, %2" : "=v"(r.y) : "v"(a.z), "v"(a.w));
  asm("v_cvt_pk_bf16_f32 %0, %1, %2" : "=v"(r.z) : "v"(b.x), "v"(b.y));
  asm("v_cvt_pk_bf16_f32 %0, %1, %2" : "=v"(r.w) : "v"(b.z), "v"(b.w));
  return r;
}

__device__ __forceinline__ void ld_g2l16(const void* gsrc, void* ldst) {
  __builtin_amdgcn_global_load_lds(
      (const __attribute__((address_space(1))) unsigned int*)gsrc,
      (__attribute__((address_space(3))) unsigned int*)ldst, 16, 0, 0);
}

// ---------------- Router: fp32-exact logits, top-2, renorm weights, expert bins ----------------
__global__ __launch_bounds__(256) void router_kernel(
    const float* __restrict__ x, const float* __restrict__ gw,
    float* __restrict__ logits, int* __restrict__ cnt,
    int* __restrict__ tok, float* __restrict__ wgt)
{
  const int t   = blockIdx.x;
  const int tid = threadIdx.x;
  float4 xv = ((const float4*)(x + (size_t)t * HIDDEN))[tid];
  float p[NEXP];
#pragma unroll
  for (int e = 0; e < NEXP; ++e) {
    float4 gv = ((const float4*)(gw + (size_t)e * HIDDEN))[tid];
    p[e] = xv.x * gv.x + xv.y * gv.y + xv.z * gv.z + xv.w * gv.w;
  }
#pragma unroll
  for (int e = 0; e < NEXP; ++e) {
#pragma unroll
    for (int off = 32; off > 0; off >>= 1)
      p[e] += __shfl_down(p[e], off, 64);
  }
  __shared__ float red[4][NEXP];
  const int wv = tid >> 6, ln = tid & 63;
  if (ln == 0) {
#pragma unroll
    for (int e = 0; e < NEXP; ++e) red[wv][e] = p[e];
  }
  __syncthreads();
  if (tid == 0) {
    float l[NEXP];
#pragma unroll
    for (int e = 0; e < NEXP; ++e) {
      l[e] = red[0][e] + red[1][e] + red[2][e] + red[3][e];
      logits[(size_t)t * NEXP + e] = l[e];
    }
    int i0 = 0;
#pragma unroll
    for (int e = 1; e < NEXP; ++e) if (l[e] > l[i0]) i0 = e;
    int i1 = (i0 == 0) ? 1 : 0;
#pragma unroll
    for (int e = 0; e < NEXP; ++e) if (e != i0 && l[e] > l[i1]) i1 = e;
    float w0 = 1.f / (1.f + expf(l[i1] - l[i0]));
    float w1 = 1.f - w0;
    int s0 = atomicAdd(&cnt[i0], 1);
    tok[i0 * NTOK + s0] = t;  wgt[i0 * NTOK + s0] = w0;
    int s1 = atomicAdd(&cnt[i1], 1);
    tok[i1 * NTOK + s1] = t;  wgt[i1 * NTOK + s1] = w1;
  }
}

// ---------------- 64-padded per-expert row bases ----------------
__global__ void prefix_kernel(const int* __restrict__ cnt, int* __restrict__ base) {
  if (threadIdx.x == 0 && blockIdx.x == 0) {
    int b = 0;
#pragma unroll
    for (int e = 0; e < NEXP; ++e) { base[e] = b; b += ((cnt[e] + 63) >> 6) << 6; }
    base[NEXP] = b;
  }
}

// ---------------- fp32 -> bf16 conversion (x only) ----------------
__global__ __launch_bounds__(256) void cvt_kernel(
    const float* __restrict__ src, unsigned short* __restrict__ dst, int n4)
{
  int i = blockIdx.x * blockDim.x + threadIdx.x;
  const int stride = gridDim.x * blockDim.x;
  for (; i < n4; i += stride) {
    float4 v = ((const float4*)src)[i];
    ushort4 o;
    o.x = f2bf(v.x); o.y = f2bf(v.y); o.z = f2bf(v.z); o.w = f2bf(v.w);
    ((ushort4*)dst)[i] = o;
  }
}

// ---------------- GEMM1: H = silu(X W1^T) * (X W3^T), M-tile 64, N-tile 128 ----------------
// LDS layout: [rows][8 units of 16B]; unit u of row r holds global unit (u ^ (r&7)).
// X staged via linear global_load_lds with pre-swizzled global source; W1/W3 reg-staged
// (global fp32 -> cvt_pk -> ds_write_b128 at linear slot, source unit pre-swizzled).
__global__ __launch_bounds__(512, 4) void gemm1_kernel(
    const unsigned short* __restrict__ xbf,   // [NTOK][HIDDEN] bf16
    const float* __restrict__ w1f,            // [E][FFN][HIDDEN] fp32
    const float* __restrict__ w3f,
    const int* __restrict__ cnt, const int* __restrict__ base,
    const int* __restrict__ tok,
    unsigned short* __restrict__ H)           // [MAXROWS][FFN] bf16
{
  // XCD-grouped: expert = bid%8 (one expert per XCD), mt fastest within XCD.
  const int bid  = blockIdx.x;
  const int e    = bid & 7;
  const int slot = bid >> 3;            // 0..511
  const int mt   = slot & 31;           // token tile (64 rows)
  const int nt   = slot >> 5;           // 0..15 ffn tile (128 cols)
  const int n = cnt[e];
  if (mt * 64 >= n) return;
  const int t = threadIdx.x;
  const int w = t >> 6, l = t & 63;

  __shared__ unsigned short Xs [64 * 64];    // 8 KB
  __shared__ unsigned short W1s[128 * 64];   // 16 KB
  __shared__ unsigned short W3s[128 * 64];   // 16 KB

  const int rX = t >> 3;                             // staged row 0..63
  const size_t tok0 = (size_t)tok[e * NTOK + min(mt * 64 + rX, n - 1)];
  const int kp = (((t & 7) ^ ((t >> 3) & 7)) << 3);  // pre-swizzled source unit (elems)

  const float* w1e = w1f + (size_t)e * FFN_DIM * HIDDEN + (size_t)(nt * 128) * HIDDEN;
  const float* w3e = w3f + (size_t)e * FFN_DIM * HIDDEN + (size_t)(nt * 128) * HIDDEN;
  const float* w1p0 = w1e + (size_t)rX        * HIDDEN + kp;
  const float* w1p1 = w1e + (size_t)(64 + rX) * HIDDEN + kp;
  const float* w3p0 = w3e + (size_t)rX        * HIDDEN + kp;
  const float* w3p1 = w3e + (size_t)(64 + rX) * HIDDEN + kp;

  uint4* lw1a = (uint4*)((char*)W1s + t * 16);
  uint4* lw1b = (uint4*)((char*)W1s + 8192 + t * 16);
  uint4* lw3a = (uint4*)((char*)W3s + t * 16);
  uint4* lw3b = (uint4*)((char*)W3s + 8192 + t * 16);
  char* ldsX = (char*)Xs + w * 1024;    // wave-uniform base (lane adds l*16)

  f32x4 acc1[2][2], acc3[2][2];
#pragma unroll
  for (int i = 0; i < 2; ++i)
#pragma unroll
    for (int j = 0; j < 2; ++j) { acc1[i][j] = (f32x4)0.f; acc3[i][j] = (f32x4)0.f; }

  const int Moff = (w & 1) * 32;        // wave M offset (2 waves over M=64)
  const int Noff = (w >> 1) * 32;       // wave N offset (4 waves over N=128)
  const int lr = l & 15;
  const int lg = l >> 4;

  for (int kb = 0; kb < HIDDEN / 64; ++kb) {
    __syncthreads();                    // previous compute done with LDS
    ld_g2l16(xbf + tok0 * HIDDEN + kb * 64 + kp, ldsX);
    {
      const int ko = kb * 64;
      float4 a0 = *(const float4*)(w1p0 + ko);
      float4 a1 = *(const float4*)(w1p0 + ko + 4);
      float4 a2 = *(const float4*)(w1p1 + ko);
      float4 a3 = *(const float4*)(w1p1 + ko + 4);
      float4 b0 = *(const float4*)(w3p0 + ko);
      float4 b1 = *(const float4*)(w3p0 + ko + 4);
      float4 b2 = *(const float4*)(w3p1 + ko);
      float4 b3 = *(const float4*)(w3p1 + ko + 4);
      *lw1a = cvt8(a0, a1);
      *lw1b = cvt8(a2, a3);
      *lw3a = cvt8(b0, b1);
      *lw3b = cvt8(b2, b3);
    }
    __syncthreads();                    // staging complete
#pragma unroll
    for (int s = 0; s < 2; ++s) {
      const int ug = 4 * s + lg;        // global k-unit this fragment wants
      bf16x8 a[2], b1v[2], b3v[2];
#pragma unroll
      for (int mi = 0; mi < 2; ++mi) {
        const int R = Moff + mi * 16 + lr;
        a[mi] = *(const bf16x8*)&Xs[R * 64 + ((ug ^ (lr & 7)) << 3)];
      }
#pragma unroll
      for (int ni = 0; ni < 2; ++ni) {
        const int R = Noff + ni * 16 + lr;
        b1v[ni] = *(const bf16x8*)&W1s[R * 64 + ((ug ^ (lr & 7)) << 3)];
        b3v[ni] = *(const bf16x8*)&W3s[R * 64 + ((ug ^ (lr & 7)) << 3)];
      }
#pragma unroll
      for (int mi = 0; mi < 2; ++mi)
#pragma unroll
        for (int ni = 0; ni < 2; ++ni) {
          acc1[mi][ni] = __builtin_amdgcn_mfma_f32_16x16x32_bf16(a[mi], b1v[ni], acc1[mi][ni], 0, 0, 0);
          acc3[mi][ni] = __builtin_amdgcn_mfma_f32_16x16x32_bf16(a[mi], b3v[ni], acc3[mi][ni], 0, 0, 0);
        }
    }
  }

  const size_t rbase = (size_t)base[e] + (size_t)mt * 64;
#pragma unroll
  for (int mi = 0; mi < 2; ++mi)
#pragma unroll
    for (int ni = 0; ni < 2; ++ni)
#pragma unroll
      for (int j = 0; j < 4; ++j) {
        int row = Moff + mi * 16 + lg * 4 + j;
        int col = nt * 128 + Noff + ni * 16 + lr;
        float s1 = acc1[mi][ni][j], s3 = acc3[mi][ni][j];
        float h = (s1 / (1.f + __expf(-s1))) * s3;      // silu(s1)*s3
        H[(rbase + row) * FFN_DIM + col] = f2bf(h);
      }
}

// ---------------- GEMM2: Y = H W2^T, M-tile 64, N-tile 128, split-K x2 ----------------
__global__ __launch_bounds__(512, 4) void gemm2_kernel(
    const unsigned short* __restrict__ H,
    const float* __restrict__ w2f,            // [E][HIDDEN][FFN] fp32
    const int* __restrict__ cnt, const int* __restrict__ base,
    const int* __restrict__ tok, const float* __restrict__ wgt,
    float* __restrict__ out)
{
  const int bid  = blockIdx.x;
  const int e    = bid & 7;
  const int slot = bid >> 3;            // 0..511
  const int mt   = slot & 31;           // token tile (64 rows)
  const int nt   = (slot >> 5) & 7;     // hidden tile (128 cols)
  const int sk   = slot >> 8;           // split-K index 0..1
  const int n = cnt[e];
  if (mt * 64 >= n) return;
  const int t = threadIdx.x;
  const int w = t >> 6, l = t & 63;

  __shared__ unsigned short Hs[64 * 64];     // 8 KB
  __shared__ unsigned short Ws[128 * 64];    // 16 KB
  __shared__ int   stok[64];
  __shared__ float swgt[64];

  if (t < 64) {
    int idx = mt * 64 + t;
    int ok = idx < n;
    stok[t] = ok ? tok[e * NTOK + idx] : -1;
    swgt[t] = ok ? wgt[e * NTOK + idx] : 0.f;
  }

  const int rH = t >> 3;
  const int kp = (((t & 7) ^ ((t >> 3) & 7)) << 3);
  const unsigned short* He = H + (size_t)(base[e] + mt * 64) * FFN_DIM;
  const float* w2e  = w2f + (size_t)e * HIDDEN * FFN_DIM + (size_t)(nt * 128) * FFN_DIM;
  const float* w2p0 = w2e + (size_t)rH        * FFN_DIM + kp;
  const float* w2p1 = w2e + (size_t)(64 + rH) * FFN_DIM + kp;

  uint4* lwa = (uint4*)((char*)Ws + t * 16);
  uint4* lwb = (uint4*)((char*)Ws + 8192 + t * 16);
  char* ldsH = (char*)Hs + w * 1024;

  f32x4 acc[2][2];
#pragma unroll
  for (int i = 0; i < 2; ++i)
#pragma unroll
    for (int j = 0; j < 2; ++j) acc[i][j] = (f32x4)0.f;

  const int Moff = (w & 1) * 32;
  const int Noff = (w >> 1) * 32;
  const int lr = l & 15;
  const int lg = l >> 4;
  const int kbase = sk * (FFN_DIM / 2);      // this block's K range start (elems)

  for (int kb = 0; kb < FFN_DIM / 2 / 64; ++kb) {
    __syncthreads();
    const int ko = kbase + kb * 64;
    ld_g2l16(He + (size_t)rH * FFN_DIM + ko + kp, ldsH);
    {
      float4 a0 = *(const float4*)(w2p0 + ko);
      float4 a1 = *(const float4*)(w2p0 + ko + 4);
      float4 a2 = *(const float4*)(w2p1 + ko);
      float4 a3 = *(const float4*)(w2p1 + ko + 4);
      *lwa = cvt8(a0, a1);
      *lwb = cvt8(a2, a3);
    }
    __syncthreads();
#pragma unroll
    for (int s = 0; s < 2; ++s) {
      const int ug = 4 * s + lg;
      bf16x8 a[2], b[2];
#pragma unroll
      for (int mi = 0; mi < 2; ++mi) {
        const int R = Moff + mi * 16 + lr;
        a[mi] = *(const bf16x8*)&Hs[R * 64 + ((ug ^ (lr & 7)) << 3)];
      }
#pragma unroll
      for (int ni = 0; ni < 2; ++ni) {
        const int R = Noff + ni * 16 + lr;
        b[ni] = *(const bf16x8*)&Ws[R * 64 + ((ug ^ (lr & 7)) << 3)];
      }
#pragma unroll
      for (int mi = 0; mi < 2; ++mi)
#pragma unroll
        for (int ni = 0; ni < 2; ++ni)
          acc[mi][ni] = __builtin_amdgcn_mfma_f32_16x16x32_bf16(a[mi], b[ni], acc[mi][ni], 0, 0, 0);
    }
  }

#pragma unroll
  for (int mi = 0; mi < 2; ++mi)
#pragma unroll
    for (int ni = 0; ni < 2; ++ni)
#pragma unroll
      for (int j = 0; j < 4; ++j) {
        int row = Moff + mi * 16 + lg * 4 + j;
        int tk = stok[row];
        if (tk >= 0) {
          int col = nt * 128 + Noff + ni * 16 + lr;
          atomicAdd(&out[(size_t)tk * HIDDEN + col], swgt[row] * acc[mi][ni][j]);
        }
      }
}

// ================= fp32 fallback path (used only if ws too small) =================
#define TT 12
#define FC 256
#define NCHUNK (FFN_DIM / FC)

__global__ __launch_bounds__(256) void moe_ffn_kernel(
    const float* __restrict__ x,
    const float* __restrict__ w1, const float* __restrict__ w2,
    const float* __restrict__ w3,
    const int* __restrict__ cnt, const int* __restrict__ tok,
    const float* __restrict__ wgt, float* __restrict__ out)
{
  const int e  = blockIdx.y;
  const int n  = cnt[e];
  const int ts = blockIdx.x * TT;
  if (ts >= n) return;
  const int tid = threadIdx.x;

  __shared__ float xs[TT * HIDDEN];
  __shared__ float hc[TT * FC];
  __shared__ int   stok[TT];
  __shared__ float swgt[TT];

  if (tid < TT) {
    int idx = ts + tid;
    int tk  = (idx < n) ? tok[e * NTOK + idx] : -1;
    stok[tid] = tk;
    swgt[tid] = (idx < n) ? wgt[e * NTOK + idx] : 0.f;
  }
  __syncthreads();
#pragma unroll
  for (int i = 0; i < TT; ++i) {
    int tk = stok[i];
    float4 v = make_float4(0.f, 0.f, 0.f, 0.f);
    if (tk >= 0) v = ((const float4*)(x + (size_t)tk * HIDDEN))[tid];
    ((float4*)(xs + i * HIDDEN))[tid] = v;
  }
  __syncthreads();

  const float* w1e = w1 + (size_t)e * FFN_DIM * HIDDEN;
  const float* w3e = w3 + (size_t)e * FFN_DIM * HIDDEN;
  const float* w2e = w2 + (size_t)e * HIDDEN * FFN_DIM;

  float yacc[4][TT];
#pragma unroll
  for (int j = 0; j < 4; ++j)
#pragma unroll
    for (int t = 0; t < TT; ++t) yacc[j][t] = 0.f;

  for (int c = 0; c < NCHUNK; ++c) {
    const int f = c * FC + tid;
    const float4* r1 = (const float4*)(w1e + (size_t)f * HIDDEN);
    const float4* r3 = (const float4*)(w3e + (size_t)f * HIDDEN);
    float a1[TT], a3[TT];
#pragma unroll
    for (int t = 0; t < TT; ++t) { a1[t] = 0.f; a3[t] = 0.f; }
    for (int k = 0; k < HIDDEN / 4; ++k) {
      float4 v1 = r1[k];
      float4 v3 = r3[k];
#pragma unroll
      for (int t = 0; t < TT; ++t) {
        float4 xv = *(const float4*)(xs + t * HIDDEN + 4 * k);
        a1[t] += xv.x * v1.x + xv.y * v1.y + xv.z * v1.z + xv.w * v1.w;
        a3[t] += xv.x * v3.x + xv.y * v3.y + xv.z * v3.z + xv.w * v3.w;
      }
    }
    __syncthreads();
#pragma unroll
    for (int t = 0; t < TT; ++t) {
      float g  = a1[t];
      float sg = g / (1.f + __expf(-g));
      hc[t * FC + tid] = sg * a3[t];
    }
    __syncthreads();
    const float4* r20 = (const float4*)(w2e + (size_t)(tid      ) * FFN_DIM + c * FC);
    const float4* r21 = (const float4*)(w2e + (size_t)(tid + 256) * FFN_DIM + c * FC);
    const float4* r22 = (const float4*)(w2e + (size_t)(tid + 512) * FFN_DIM + c * FC);
    const float4* r23 = (const float4*)(w2e + (size_t)(tid + 768) * FFN_DIM + c * FC);
    for (int k = 0; k < FC / 4; ++k) {
      float4 wv0 = r20[k], wv1 = r21[k], wv2 = r22[k], wv3 = r23[k];
#pragma unroll
      for (int t = 0; t < TT; ++t) {
        float4 hv = *(const float4*)(hc + t * FC + 4 * k);
        yacc[0][t] += hv.x * wv0.x + hv.y * wv0.y + hv.z * wv0.z + hv.w * wv0.w;
        yacc[1][t] += hv.x * wv1.x + hv.y * wv1.y + hv.z * wv1.z + hv.w * wv1.w;
        yacc[2][t] += hv.x * wv2.x + hv.y * wv2.y + hv.z * wv2.z + hv.w * wv2.w;
        yacc[3][t] += hv.x * wv3.x + hv.y * wv3.y + hv.z * wv3.z + hv.w * wv3.w;
      }
    }
  }

#pragma unroll
  for (int t = 0; t < TT; ++t) {
    int tk = stok[t];
    if (tk < 0) continue;
    float wt = swgt[t];
    float* orow = out + (size_t)tk * HIDDEN;
    atomicAdd(orow + tid,       wt * yacc[0][t]);
    atomicAdd(orow + tid + 256, wt * yacc[1][t]);
    atomicAdd(orow + tid + 512, wt * yacc[2][t]);
    atomicAdd(orow + tid + 768, wt * yacc[3][t]);
  }
}

extern "C" void kernel_launch(void* const* d_in, const int* in_sizes, int n_in,
                              void* d_out, int out_size, void* d_ws, size_t ws_size,
                              hipStream_t stream) {
  const float* x  = (const float*)d_in[0];
  const float* gw = (const float*)d_in[1];
  const float* w1 = (const float*)d_in[2];
  const float* w2 = (const float*)d_in[3];
  const float* w3 = (const float*)d_in[4];
  float* out    = (float*)d_out;
  float* logits = out + (size_t)NTOK * HIDDEN;

  char* ws = (char*)d_ws;
  int*   cnt  = (int*)(ws + OFF_CNT);
  int*   base = (int*)(ws + OFF_BASE);
  int*   tokp = (int*)(ws + OFF_TOK);
  float* wgtp = (float*)(ws + OFF_WGT);

  hipMemsetAsync(out, 0, (size_t)NTOK * HIDDEN * sizeof(float), stream);
  hipMemsetAsync(cnt, 0, NEXP * sizeof(int), stream);

  router_kernel<<<NTOK, 256, 0, stream>>>(x, gw, logits, cnt, tokp, wgtp);

  if (ws_size >= WS_NEED) {
    unsigned short* xbf  = (unsigned short*)(ws + OFF_XBF);
    unsigned short* Hbuf = (unsigned short*)(ws + OFF_H);

    cvt_kernel<<<512, 256, 0, stream>>>(x, xbf, (int)(NTOK * HIDDEN / 4));
    prefix_kernel<<<1, 64, 0, stream>>>(cnt, base);

    // worst-case grids (balanced case: 1024 active blocks each = 4/CU)
    gemm1_kernel<<<NEXP * 32 * 16, 512, 0, stream>>>(xbf, w1, w3, cnt, base, tokp, Hbuf);
    gemm2_kernel<<<NEXP * 32 * 8 * 2, 512, 0, stream>>>(Hbuf, w2, cnt, base, tokp, wgtp, out);
  } else {
    dim3 grid((NTOK + TT - 1) / TT, NEXP);
    moe_ffn_kernel<<<grid, 256, 0, stream>>>(x, w1, w2, w3, cnt, tokp, wgtp, out);
  }
}

// Round 6
// 209.049 us; speedup vs baseline: 1.0862x; 1.0403x over previous
//
#include <hip/hip_runtime.h>
#include <hip/hip_bf16.h>
#include <stdint.h>

#define HIDDEN  1024
#define FFN_DIM 2048
#define NEXP    8
#define NTOK    2048          // B*S
#define MAXROWS 5120          // sum of 128-padded per-expert counts <= 4096 + 8*127

typedef short bf16x8 __attribute__((ext_vector_type(8)));
typedef float f32x4  __attribute__((ext_vector_type(4)));

// ---------------- ws layout (bytes) ----------------
static const size_t OFF_CNT  = 0;                         // 8 ints
static const size_t OFF_BASE = 64;                        // 9 ints
static const size_t OFF_TOK  = 128;                       // 8*2048 ints
static const size_t OFF_WGT  = OFF_TOK + (size_t)NEXP*NTOK*4;
static const size_t OFF_XBF  = 131328;                    // 256-aligned
static const size_t XBF_B    = (size_t)NTOK*HIDDEN*2;
static const size_t OFF_H    = OFF_XBF + XBF_B;
static const size_t H_B      = (size_t)MAXROWS*FFN_DIM*2;
static const size_t WS_NEED  = OFF_H + H_B;               // ~25 MB

__device__ __forceinline__ unsigned short f2bf(float f) {
  union { float f; unsigned u; } a; a.f = f;
  unsigned r = a.u + 0x7fff + ((a.u >> 16) & 1);          // RTN-even
  return (unsigned short)(r >> 16);
}

// 8 fp32 -> 8 bf16 packed in a uint4 (memory order preserved)
__device__ __forceinline__ uint4 cvt8(float4 a, float4 b) {
  uint4 r;
  asm("v_cvt_pk_bf16_f32 %0, %1, %2" : "=v"(r.x) : "v"(a.x), "v"(a.y));
  asm("v_cvt_pk_bf16_f32 %0, %1, %2" : "=v"(r.y) : "v"(a.z), "v"(a.w));
  asm("v_cvt_pk_bf16_f32 %0, %1, %2" : "=v"(r.z) : "v"(b.x), "v"(b.y));
  asm("v_cvt_pk_bf16_f32 %0, %1, %2" : "=v"(r.w) : "v"(b.z), "v"(b.w));
  return r;
}

__device__ __forceinline__ void ld_g2l16(const void* gsrc, void* ldst) {
  __builtin_amdgcn_global_load_lds(
      (const __attribute__((address_space(1))) unsigned int*)gsrc,
      (__attribute__((address_space(3))) unsigned int*)ldst, 16, 0, 0);
}

// ---------------- Router: fp32-exact logits, top-2, renorm weights, bins; also writes x as bf16 --
__global__ __launch_bounds__(256) void router_kernel(
    const float* __restrict__ x, const float* __restrict__ gw,
    float* __restrict__ logits, int* __restrict__ cnt,
    int* __restrict__ tok, float* __restrict__ wgt,
    unsigned short* __restrict__ xbf)
{
  const int t   = blockIdx.x;
  const int tid = threadIdx.x;
  float4 xv = ((const float4*)(x + (size_t)t * HIDDEN))[tid];
  if (xbf) {                                   // fused fp32->bf16 of x
    ushort4 o;
    o.x = f2bf(xv.x); o.y = f2bf(xv.y); o.z = f2bf(xv.z); o.w = f2bf(xv.w);
    ((ushort4*)(xbf + (size_t)t * HIDDEN))[tid] = o;
  }
  float p[NEXP];
#pragma unroll
  for (int e = 0; e < NEXP; ++e) {
    float4 gv = ((const float4*)(gw + (size_t)e * HIDDEN))[tid];
    p[e] = xv.x * gv.x + xv.y * gv.y + xv.z * gv.z + xv.w * gv.w;
  }
#pragma unroll
  for (int e = 0; e < NEXP; ++e) {
#pragma unroll
    for (int off = 32; off > 0; off >>= 1)
      p[e] += __shfl_down(p[e], off, 64);
  }
  __shared__ float red[4][NEXP];
  const int wv = tid >> 6, ln = tid & 63;
  if (ln == 0) {
#pragma unroll
    for (int e = 0; e < NEXP; ++e) red[wv][e] = p[e];
  }
  __syncthreads();
  if (tid == 0) {
    float l[NEXP];
#pragma unroll
    for (int e = 0; e < NEXP; ++e) {
      l[e] = red[0][e] + red[1][e] + red[2][e] + red[3][e];
      logits[(size_t)t * NEXP + e] = l[e];
    }
    int i0 = 0;
#pragma unroll
    for (int e = 1; e < NEXP; ++e) if (l[e] > l[i0]) i0 = e;
    int i1 = (i0 == 0) ? 1 : 0;
#pragma unroll
    for (int e = 0; e < NEXP; ++e) if (e != i0 && l[e] > l[i1]) i1 = e;
    float w0 = 1.f / (1.f + expf(l[i1] - l[i0]));
    float w1 = 1.f - w0;
    int s0 = atomicAdd(&cnt[i0], 1);
    tok[i0 * NTOK + s0] = t;  wgt[i0 * NTOK + s0] = w0;
    int s1 = atomicAdd(&cnt[i1], 1);
    tok[i1 * NTOK + s1] = t;  wgt[i1 * NTOK + s1] = w1;
  }
}

// ---------------- 128-padded per-expert row bases ----------------
__global__ void prefix_kernel(const int* __restrict__ cnt, int* __restrict__ base) {
  if (threadIdx.x == 0 && blockIdx.x == 0) {
    int b = 0;
#pragma unroll
    for (int e = 0; e < NEXP; ++e) { base[e] = b; b += ((cnt[e] + 127) >> 7) << 7; }
    base[NEXP] = b;
  }
}

// ---------------- GEMM1: H = silu(X W1^T) * (X W3^T) -----------------------------------------
// M=128 (tokens), N=64 (ffn), K-step 64. Single-barrier double-buffered pipeline:
// per step {issue g2l-X(k+1) + fp32 W reg-loads(k+1)} -> MFMA(k) -> cvt+ds_write(k+1) -> barrier.
// LDS swizzle: unit u of row r holds global unit u^(r&7) (src pre-swizzled, reads XOR same key).
#define G1_COMPUTE(BUF)                                                                           \
  {                                                                                               \
    const unsigned short* Xc  = Xs[BUF];                                                          \
    const unsigned short* W1c = W1s[BUF];                                                         \
    const unsigned short* W3c = W3s[BUF];                                                         \
    _Pragma("unroll")                                                                             \
    for (int s = 0; s < 2; ++s) {                                                                 \
      const int sw = (((4 * s + lg) ^ (lr & 7)) << 3);                                            \
      bf16x8 a0v = *(const bf16x8*)&Xc[(Moff + lr) * 64 + sw];                                    \
      bf16x8 a1v = *(const bf16x8*)&Xc[(Moff + 16 + lr) * 64 + sw];                               \
      bf16x8 p0  = *(const bf16x8*)&W1c[(Noff + lr) * 64 + sw];                                   \
      bf16x8 p1  = *(const bf16x8*)&W1c[(Noff + 16 + lr) * 64 + sw];                              \
      bf16x8 q0  = *(const bf16x8*)&W3c[(Noff + lr) * 64 + sw];                                   \
      bf16x8 q1  = *(const bf16x8*)&W3c[(Noff + 16 + lr) * 64 + sw];                              \
      acc1[0][0] = __builtin_amdgcn_mfma_f32_16x16x32_bf16(a0v, p0, acc1[0][0], 0, 0, 0);         \
      acc1[0][1] = __builtin_amdgcn_mfma_f32_16x16x32_bf16(a0v, p1, acc1[0][1], 0, 0, 0);         \
      acc1[1][0] = __builtin_amdgcn_mfma_f32_16x16x32_bf16(a1v, p0, acc1[1][0], 0, 0, 0);         \
      acc1[1][1] = __builtin_amdgcn_mfma_f32_16x16x32_bf16(a1v, p1, acc1[1][1], 0, 0, 0);         \
      acc3[0][0] = __builtin_amdgcn_mfma_f32_16x16x32_bf16(a0v, q0, acc3[0][0], 0, 0, 0);         \
      acc3[0][1] = __builtin_amdgcn_mfma_f32_16x16x32_bf16(a0v, q1, acc3[0][1], 0, 0, 0);         \
      acc3[1][0] = __builtin_amdgcn_mfma_f32_16x16x32_bf16(a1v, q0, acc3[1][0], 0, 0, 0);         \
      acc3[1][1] = __builtin_amdgcn_mfma_f32_16x16x32_bf16(a1v, q1, acc3[1][1], 0, 0, 0);         \
    }                                                                                             \
  }

__global__ __launch_bounds__(512, 4) void gemm1_kernel(
    const unsigned short* __restrict__ xbf,   // [NTOK][HIDDEN] bf16
    const float* __restrict__ w1f,            // [E][FFN][HIDDEN] fp32
    const float* __restrict__ w3f,
    const int* __restrict__ cnt, const int* __restrict__ base,
    const int* __restrict__ tok,
    unsigned short* __restrict__ H)           // [MAXROWS][FFN] bf16
{
  // XCD-grouped: expert = bid%8 (one expert per XCD), mt fastest within XCD.
  const int bid  = blockIdx.x;
  const int e    = bid & 7;
  const int slot = bid >> 3;            // 0..511
  const int mt   = slot & 15;           // 128-row token tile
  const int nt   = slot >> 4;           // 0..31, 64-col ffn tile
  const int n = cnt[e];
  if (mt * 128 >= n) return;
  const int t = threadIdx.x;
  const int w = t >> 6, l = t & 63;

  __shared__ unsigned short Xs [2][128 * 64];   // 2 x 16 KB
  __shared__ unsigned short W1s[2][64 * 64];    // 2 x 8 KB
  __shared__ unsigned short W3s[2][64 * 64];    // 2 x 8 KB

  const int rX = t >> 3;
  const size_t tok0 = (size_t)tok[e * NTOK + min(mt * 128 + rX, n - 1)];
  const size_t tok1 = (size_t)tok[e * NTOK + min(mt * 128 + 64 + rX, n - 1)];
  const int kp = (((t & 7) ^ ((t >> 3) & 7)) << 3);  // pre-swizzled source unit (elems)

  const float* w1p = w1f + (size_t)e * FFN_DIM * HIDDEN + ((size_t)nt * 64 + rX) * HIDDEN + kp;
  const float* w3p = w3f + (size_t)e * FFN_DIM * HIDDEN + ((size_t)nt * 64 + rX) * HIDDEN + kp;

  f32x4 acc1[2][2], acc3[2][2];
#pragma unroll
  for (int i = 0; i < 2; ++i)
#pragma unroll
    for (int j = 0; j < 2; ++j) { acc1[i][j] = (f32x4)0.f; acc3[i][j] = (f32x4)0.f; }

  const int Moff = (w & 3) * 32;        // 4 waves over M=128
  const int Noff = (w >> 2) * 32;       // 2 waves over N=64
  const int lr = l & 15;
  const int lg = l >> 4;

  // prologue: stage tile 0 into buffer 0
  ld_g2l16(xbf + tok0 * HIDDEN + kp, (char*)Xs[0] + w * 1024);
  ld_g2l16(xbf + tok1 * HIDDEN + kp, (char*)Xs[0] + 8192 + w * 1024);
  {
    float4 a0 = *(const float4*)(w1p);
    float4 a1 = *(const float4*)(w1p + 4);
    float4 b0 = *(const float4*)(w3p);
    float4 b1 = *(const float4*)(w3p + 4);
    *(uint4*)((char*)W1s[0] + t * 16) = cvt8(a0, a1);
    *(uint4*)((char*)W3s[0] + t * 16) = cvt8(b0, b1);
  }
  __syncthreads();

  int cur = 0;
  for (int kb = 0; kb < HIDDEN / 64 - 1; ++kb) {
    const int ko = (kb + 1) * 64;
    // issue next tile's loads (latency rides under MFMA phase)
    ld_g2l16(xbf + tok0 * HIDDEN + ko + kp, (char*)Xs[cur ^ 1] + w * 1024);
    ld_g2l16(xbf + tok1 * HIDDEN + ko + kp, (char*)Xs[cur ^ 1] + 8192 + w * 1024);
    float4 a0 = *(const float4*)(w1p + ko);
    float4 a1 = *(const float4*)(w1p + ko + 4);
    float4 b0 = *(const float4*)(w3p + ko);
    float4 b1 = *(const float4*)(w3p + ko + 4);
    G1_COMPUTE(cur);
    // write next tile's W (waits for the loads here, after MFMA)
    *(uint4*)((char*)W1s[cur ^ 1] + t * 16) = cvt8(a0, a1);
    *(uint4*)((char*)W3s[cur ^ 1] + t * 16) = cvt8(b0, b1);
    __syncthreads();                    // single barrier per K-step
    cur ^= 1;
  }
  G1_COMPUTE(cur);                      // final tile, no staging

  const size_t rbase = (size_t)base[e] + (size_t)mt * 128;
#pragma unroll
  for (int mi = 0; mi < 2; ++mi)
#pragma unroll
    for (int ni = 0; ni < 2; ++ni)
#pragma unroll
      for (int j = 0; j < 4; ++j) {
        int row = Moff + mi * 16 + lg * 4 + j;
        int col = nt * 64 + Noff + ni * 16 + lr;
        float s1 = acc1[mi][ni][j], s3 = acc3[mi][ni][j];
        float h = (s1 / (1.f + __expf(-s1))) * s3;      // silu(s1)*s3
        H[(rbase + row) * FFN_DIM + col] = f2bf(h);
      }
}

// ---------------- GEMM2: Y = H W2^T, M=64, N=128, split-K x2, same pipeline -------------------
#define G2_COMPUTE(BUF)                                                                           \
  {                                                                                               \
    const unsigned short* Hc = Hs[BUF];                                                           \
    const unsigned short* Wc = Ws[BUF];                                                           \
    _Pragma("unroll")                                                                             \
    for (int s = 0; s < 2; ++s) {                                                                 \
      const int sw = (((4 * s + lg) ^ (lr & 7)) << 3);                                            \
      bf16x8 a0v = *(const bf16x8*)&Hc[(Moff + lr) * 64 + sw];                                    \
      bf16x8 a1v = *(const bf16x8*)&Hc[(Moff + 16 + lr) * 64 + sw];                               \
      bf16x8 p0  = *(const bf16x8*)&Wc[(Noff + lr) * 64 + sw];                                    \
      bf16x8 p1  = *(const bf16x8*)&Wc[(Noff + 16 + lr) * 64 + sw];                               \
      acc[0][0] = __builtin_amdgcn_mfma_f32_16x16x32_bf16(a0v, p0, acc[0][0], 0, 0, 0);           \
      acc[0][1] = __builtin_amdgcn_mfma_f32_16x16x32_bf16(a0v, p1, acc[0][1], 0, 0, 0);           \
      acc[1][0] = __builtin_amdgcn_mfma_f32_16x16x32_bf16(a1v, p0, acc[1][0], 0, 0, 0);           \
      acc[1][1] = __builtin_amdgcn_mfma_f32_16x16x32_bf16(a1v, p1, acc[1][1], 0, 0, 0);           \
    }                                                                                             \
  }

__global__ __launch_bounds__(512, 4) void gemm2_kernel(
    const unsigned short* __restrict__ H,
    const float* __restrict__ w2f,            // [E][HIDDEN][FFN] fp32
    const int* __restrict__ cnt, const int* __restrict__ base,
    const int* __restrict__ tok, const float* __restrict__ wgt,
    float* __restrict__ out)
{
  const int bid  = blockIdx.x;
  const int e    = bid & 7;
  const int slot = bid >> 3;            // 0..511
  const int mt   = slot & 31;           // 64-row token tile
  const int nt   = (slot >> 5) & 7;     // 128-col hidden tile
  const int sk   = slot >> 8;           // split-K 0..1
  const int n = cnt[e];
  if (mt * 64 >= n) return;
  const int t = threadIdx.x;
  const int w = t >> 6, l = t & 63;

  __shared__ unsigned short Hs[2][64 * 64];    // 2 x 8 KB
  __shared__ unsigned short Ws[2][128 * 64];   // 2 x 16 KB
  __shared__ int   stok[64];
  __shared__ float swgt[64];

  if (t < 64) {
    int idx = mt * 64 + t;
    int ok = idx < n;
    stok[t] = ok ? tok[e * NTOK + idx] : -1;
    swgt[t] = ok ? wgt[e * NTOK + idx] : 0.f;
  }

  const int rH = t >> 3;
  const int kp = (((t & 7) ^ ((t >> 3) & 7)) << 3);
  const unsigned short* Hp = H + (size_t)(base[e] + mt * 64 + rH) * FFN_DIM + sk * (FFN_DIM / 2) + kp;
  const float* w2b  = w2f + (size_t)e * HIDDEN * FFN_DIM + sk * (FFN_DIM / 2) + kp;
  const float* w2p0 = w2b + ((size_t)nt * 128 + rH) * FFN_DIM;
  const float* w2p1 = w2b + ((size_t)nt * 128 + 64 + rH) * FFN_DIM;

  f32x4 acc[2][2];
#pragma unroll
  for (int i = 0; i < 2; ++i)
#pragma unroll
    for (int j = 0; j < 2; ++j) acc[i][j] = (f32x4)0.f;

  const int Moff = (w & 1) * 32;        // 2 waves over M=64
  const int Noff = (w >> 1) * 32;       // 4 waves over N=128
  const int lr = l & 15;
  const int lg = l >> 4;

  // prologue: stage tile 0
  ld_g2l16(Hp, (char*)Hs[0] + w * 1024);
  {
    float4 a0 = *(const float4*)(w2p0);
    float4 a1 = *(const float4*)(w2p0 + 4);
    float4 a2 = *(const float4*)(w2p1);
    float4 a3 = *(const float4*)(w2p1 + 4);
    *(uint4*)((char*)Ws[0] + t * 16)        = cvt8(a0, a1);
    *(uint4*)((char*)Ws[0] + 8192 + t * 16) = cvt8(a2, a3);
  }
  __syncthreads();

  int cur = 0;
  for (int kb = 0; kb < FFN_DIM / 2 / 64 - 1; ++kb) {
    const int ko = (kb + 1) * 64;
    ld_g2l16(Hp + ko, (char*)Hs[cur ^ 1] + w * 1024);
    float4 a0 = *(const float4*)(w2p0 + ko);
    float4 a1 = *(const float4*)(w2p0 + ko + 4);
    float4 a2 = *(const float4*)(w2p1 + ko);
    float4 a3 = *(const float4*)(w2p1 + ko + 4);
    G2_COMPUTE(cur);
    *(uint4*)((char*)Ws[cur ^ 1] + t * 16)        = cvt8(a0, a1);
    *(uint4*)((char*)Ws[cur ^ 1] + 8192 + t * 16) = cvt8(a2, a3);
    __syncthreads();
    cur ^= 1;
  }
  G2_COMPUTE(cur);

#pragma unroll
  for (int mi = 0; mi < 2; ++mi)
#pragma unroll
    for (int ni = 0; ni < 2; ++ni)
#pragma unroll
      for (int j = 0; j < 4; ++j) {
        int row = Moff + mi * 16 + lg * 4 + j;
        int tk = stok[row];
        if (tk >= 0) {
          int col = nt * 128 + Noff + ni * 16 + lr;
          atomicAdd(&out[(size_t)tk * HIDDEN + col], swgt[row] * acc[mi][ni][j]);
        }
      }
}

// ================= fp32 fallback path (used only if ws too small) =================
#define TT 12
#define FC 256
#define NCHUNK (FFN_DIM / FC)

__global__ __launch_bounds__(256) void moe_ffn_kernel(
    const float* __restrict__ x,
    const float* __restrict__ w1, const float* __restrict__ w2,
    const float* __restrict__ w3,
    const int* __restrict__ cnt, const int* __restrict__ tok,
    const float* __restrict__ wgt, float* __restrict__ out)
{
  const int e  = blockIdx.y;
  const int n  = cnt[e];
  const int ts = blockIdx.x * TT;
  if (ts >= n) return;
  const int tid = threadIdx.x;

  __shared__ float xs[TT * HIDDEN];
  __shared__ float hc[TT * FC];
  __shared__ int   stok[TT];
  __shared__ float swgt[TT];

  if (tid < TT) {
    int idx = ts + tid;
    int tk  = (idx < n) ? tok[e * NTOK + idx] : -1;
    stok[tid] = tk;
    swgt[tid] = (idx < n) ? wgt[e * NTOK + idx] : 0.f;
  }
  __syncthreads();
#pragma unroll
  for (int i = 0; i < TT; ++i) {
    int tk = stok[i];
    float4 v = make_float4(0.f, 0.f, 0.f, 0.f);
    if (tk >= 0) v = ((const float4*)(x + (size_t)tk * HIDDEN))[tid];
    ((float4*)(xs + i * HIDDEN))[tid] = v;
  }
  __syncthreads();

  const float* w1e = w1 + (size_t)e * FFN_DIM * HIDDEN;
  const float* w3e = w3 + (size_t)e * FFN_DIM * HIDDEN;
  const float* w2e = w2 + (size_t)e * HIDDEN * FFN_DIM;

  float yacc[4][TT];
#pragma unroll
  for (int j = 0; j < 4; ++j)
#pragma unroll
    for (int t = 0; t < TT; ++t) yacc[j][t] = 0.f;

  for (int c = 0; c < NCHUNK; ++c) {
    const int f = c * FC + tid;
    const float4* r1 = (const float4*)(w1e + (size_t)f * HIDDEN);
    const float4* r3 = (const float4*)(w3e + (size_t)f * HIDDEN);
    float a1[TT], a3[TT];
#pragma unroll
    for (int t = 0; t < TT; ++t) { a1[t] = 0.f; a3[t] = 0.f; }
    for (int k = 0; k < HIDDEN / 4; ++k) {
      float4 v1 = r1[k];
      float4 v3 = r3[k];
#pragma unroll
      for (int t = 0; t < TT; ++t) {
        float4 xv = *(const float4*)(xs + t * HIDDEN + 4 * k);
        a1[t] += xv.x * v1.x + xv.y * v1.y + xv.z * v1.z + xv.w * v1.w;
        a3[t] += xv.x * v3.x + xv.y * v3.y + xv.z * v3.z + xv.w * v3.w;
      }
    }
    __syncthreads();
#pragma unroll
    for (int t = 0; t < TT; ++t) {
      float g  = a1[t];
      float sg = g / (1.f + __expf(-g));
      hc[t * FC + tid] = sg * a3[t];
    }
    __syncthreads();
    const float4* r20 = (const float4*)(w2e + (size_t)(tid      ) * FFN_DIM + c * FC);
    const float4* r21 = (const float4*)(w2e + (size_t)(tid + 256) * FFN_DIM + c * FC);
    const float4* r22 = (const float4*)(w2e + (size_t)(tid + 512) * FFN_DIM + c * FC);
    const float4* r23 = (const float4*)(w2e + (size_t)(tid + 768) * FFN_DIM + c * FC);
    for (int k = 0; k < FC / 4; ++k) {
      float4 wv0 = r20[k], wv1 = r21[k], wv2 = r22[k], wv3 = r23[k];
#pragma unroll
      for (int t = 0; t < TT; ++t) {
        float4 hv = *(const float4*)(hc + t * FC + 4 * k);
        yacc[0][t] += hv.x * wv0.x + hv.y * wv0.y + hv.z * wv0.z + hv.w * wv0.w;
        yacc[1][t] += hv.x * wv1.x + hv.y * wv1.y + hv.z * wv1.z + hv.w * wv1.w;
        yacc[2][t] += hv.x * wv2.x + hv.y * wv2.y + hv.z * wv2.z + hv.w * wv2.w;
        yacc[3][t] += hv.x * wv3.x + hv.y * wv3.y + hv.z * wv3.z + hv.w * wv3.w;
      }
    }
  }

#pragma unroll
  for (int t = 0; t < TT; ++t) {
    int tk = stok[t];
    if (tk < 0) continue;
    float wt = swgt[t];
    float* orow = out + (size_t)tk * HIDDEN;
    atomicAdd(orow + tid,       wt * yacc[0][t]);
    atomicAdd(orow + tid + 256, wt * yacc[1][t]);
    atomicAdd(orow + tid + 512, wt * yacc[2][t]);
    atomicAdd(orow + tid + 768, wt * yacc[3][t]);
  }
}

extern "C" void kernel_launch(void* const* d_in, const int* in_sizes, int n_in,
                              void* d_out, int out_size, void* d_ws, size_t ws_size,
                              hipStream_t stream) {
  const float* x  = (const float*)d_in[0];
  const float* gw = (const float*)d_in[1];
  const float* w1 = (const float*)d_in[2];
  const float* w2 = (const float*)d_in[3];
  const float* w3 = (const float*)d_in[4];
  float* out    = (float*)d_out;
  float* logits = out + (size_t)NTOK * HIDDEN;

  char* ws = (char*)d_ws;
  int*   cnt  = (int*)(ws + OFF_CNT);
  int*   base = (int*)(ws + OFF_BASE);
  int*   tokp = (int*)(ws + OFF_TOK);
  float* wgtp = (float*)(ws + OFF_WGT);

  const bool big = (ws_size >= WS_NEED);
  unsigned short* xbf  = big ? (unsigned short*)(ws + OFF_XBF) : (unsigned short*)0;
  unsigned short* Hbuf = big ? (unsigned short*)(ws + OFF_H)   : (unsigned short*)0;

  hipMemsetAsync(out, 0, (size_t)NTOK * HIDDEN * sizeof(float), stream);
  hipMemsetAsync(cnt, 0, NEXP * sizeof(int), stream);

  router_kernel<<<NTOK, 256, 0, stream>>>(x, gw, logits, cnt, tokp, wgtp, xbf);

  if (big) {
    prefix_kernel<<<1, 64, 0, stream>>>(cnt, base);
    gemm1_kernel<<<NEXP * 16 * 32, 512, 0, stream>>>(xbf, w1, w3, cnt, base, tokp, Hbuf);
    gemm2_kernel<<<NEXP * 32 * 8 * 2, 512, 0, stream>>>(Hbuf, w2, cnt, base, tokp, wgtp, out);
  } else {
    dim3 grid((NTOK + TT - 1) / TT, NEXP);
    moe_ffn_kernel<<<grid, 256, 0, stream>>>(x, w1, w2, w3, cnt, tokp, wgtp, out);
  }
}

// Round 7
// 196.779 us; speedup vs baseline: 1.1539x; 1.0624x over previous
//
#include <hip/hip_runtime.h>
#include <hip/hip_bf16.h>
#include <stdint.h>

#define HIDDEN  1024
#define FFN_DIM 2048
#define NEXP    8
#define NTOK    2048          // B*S
#define MAXROWS 5120          // sum of 128-padded per-expert counts

typedef short bf16x8 __attribute__((ext_vector_type(8)));
typedef float f32x4  __attribute__((ext_vector_type(4)));

// ---------------- ws layout (bytes) ----------------
static const size_t OFF_CNT  = 0;                         // 8 ints
static const size_t OFF_BASE = 64;                        // 9 ints
static const size_t OFF_TOK  = 128;                       // 8*2048 ints
static const size_t OFF_WGT  = OFF_TOK + (size_t)NEXP*NTOK*4;
static const size_t OFF_XBF  = 131328;                    // 256-aligned
static const size_t XBF_B    = (size_t)NTOK*HIDDEN*2;
static const size_t OFF_H    = OFF_XBF + XBF_B;
static const size_t H_B      = (size_t)MAXROWS*FFN_DIM*2;
static const size_t WS_NEED  = OFF_H + H_B;               // ~25 MB

__device__ __forceinline__ unsigned short f2bf(float f) {
  union { float f; unsigned u; } a; a.f = f;
  unsigned r = a.u + 0x7fff + ((a.u >> 16) & 1);          // RTN-even
  return (unsigned short)(r >> 16);
}

// 8 fp32 -> bf16x8 via packed cvt (memory order preserved)
__device__ __forceinline__ bf16x8 cvt8b(float4 a, float4 b) {
  union { uint4 u; bf16x8 v; } r;
  asm("v_cvt_pk_bf16_f32 %0, %1, %2" : "=v"(r.u.x) : "v"(a.x), "v"(a.y));
  asm("v_cvt_pk_bf16_f32 %0, %1, %2" : "=v"(r.u.y) : "v"(a.z), "v"(a.w));
  asm("v_cvt_pk_bf16_f32 %0, %1, %2" : "=v"(r.u.z) : "v"(b.x), "v"(b.y));
  asm("v_cvt_pk_bf16_f32 %0, %1, %2" : "=v"(r.u.w) : "v"(b.z), "v"(b.w));
  return r.v;
}

__device__ __forceinline__ void ld_g2l16(const void* gsrc, void* ldst) {
  __builtin_amdgcn_global_load_lds(
      (const __attribute__((address_space(1))) unsigned int*)gsrc,
      (__attribute__((address_space(3))) unsigned int*)ldst, 16, 0, 0);
}

// ---------------- Router: fp32-exact logits, top-2, renorm weights, bins; fused x->bf16 --------
__global__ __launch_bounds__(256) void router_kernel(
    const float* __restrict__ x, const float* __restrict__ gw,
    float* __restrict__ logits, int* __restrict__ cnt,
    int* __restrict__ tok, float* __restrict__ wgt,
    unsigned short* __restrict__ xbf)
{
  const int t   = blockIdx.x;
  const int tid = threadIdx.x;
  float4 xv = ((const float4*)(x + (size_t)t * HIDDEN))[tid];
  if (xbf) {
    ushort4 o;
    o.x = f2bf(xv.x); o.y = f2bf(xv.y); o.z = f2bf(xv.z); o.w = f2bf(xv.w);
    ((ushort4*)(xbf + (size_t)t * HIDDEN))[tid] = o;
  }
  float p[NEXP];
#pragma unroll
  for (int e = 0; e < NEXP; ++e) {
    float4 gv = ((const float4*)(gw + (size_t)e * HIDDEN))[tid];
    p[e] = xv.x * gv.x + xv.y * gv.y + xv.z * gv.z + xv.w * gv.w;
  }
#pragma unroll
  for (int e = 0; e < NEXP; ++e) {
#pragma unroll
    for (int off = 32; off > 0; off >>= 1)
      p[e] += __shfl_down(p[e], off, 64);
  }
  __shared__ float red[4][NEXP];
  const int wv = tid >> 6, ln = tid & 63;
  if (ln == 0) {
#pragma unroll
    for (int e = 0; e < NEXP; ++e) red[wv][e] = p[e];
  }
  __syncthreads();
  if (tid == 0) {
    float l[NEXP];
#pragma unroll
    for (int e = 0; e < NEXP; ++e) {
      l[e] = red[0][e] + red[1][e] + red[2][e] + red[3][e];
      logits[(size_t)t * NEXP + e] = l[e];
    }
    int i0 = 0;
#pragma unroll
    for (int e = 1; e < NEXP; ++e) if (l[e] > l[i0]) i0 = e;
    int i1 = (i0 == 0) ? 1 : 0;
#pragma unroll
    for (int e = 0; e < NEXP; ++e) if (e != i0 && l[e] > l[i1]) i1 = e;
    float w0 = 1.f / (1.f + expf(l[i1] - l[i0]));
    float w1 = 1.f - w0;
    int s0 = atomicAdd(&cnt[i0], 1);
    tok[i0 * NTOK + s0] = t;  wgt[i0 * NTOK + s0] = w0;
    int s1 = atomicAdd(&cnt[i1], 1);
    tok[i1 * NTOK + s1] = t;  wgt[i1 * NTOK + s1] = w1;
  }
}

// ---------------- 128-padded per-expert row bases ----------------
__global__ void prefix_kernel(const int* __restrict__ cnt, int* __restrict__ base) {
  if (threadIdx.x == 0 && blockIdx.x == 0) {
    int b = 0;
#pragma unroll
    for (int e = 0; e < NEXP; ++e) { base[e] = b; b += ((cnt[e] + 127) >> 7) << 7; }
    base[NEXP] = b;
  }
}

// ---------------- GEMM1: H = silu(X W1^T) * (X W3^T) ------------------------------------------
// M=128 x N=64 x BK=64, 256 thr (4 waves: 2M x 2N), m97 2-barrier, ALL staging via g2l.
// X: bf16 LDS [128 rows][8 u16B], phys unit u holds global unit u^(r&7).
// W1/W3: fp32 LDS [64 rows][16 u16B], phys unit u holds global fp32-unit u^(r&15);
// fragment (8 fp32 = units {2u,2u+1}) -> 2 ds_read_b128 + cvt8b on the read path.
__global__ __launch_bounds__(256, 3) void gemm1_kernel(
    const unsigned short* __restrict__ xbf,   // [NTOK][HIDDEN] bf16
    const float* __restrict__ w1f,            // [E][FFN][HIDDEN] fp32
    const float* __restrict__ w3f,
    const int* __restrict__ cnt, const int* __restrict__ base,
    const int* __restrict__ tok,
    unsigned short* __restrict__ H)           // [MAXROWS][FFN] bf16
{
  // XCD-grouped: expert = bid%8 (one expert per XCD), mt fastest within XCD.
  const int bid  = blockIdx.x;
  const int e    = bid & 7;
  const int slot = bid >> 3;            // 0..511
  const int mt   = slot & 15;           // 128-row token tile
  const int nt   = slot >> 4;           // 0..31, 64-col ffn tile
  const int n = cnt[e];
  if (mt * 128 >= n) return;
  const int t = threadIdx.x;
  const int w = t >> 6, l = t & 63;

  __shared__ unsigned short Xs[128 * 64];    // 16 KB bf16
  __shared__ float W1s[64 * 64];             // 16 KB fp32
  __shared__ float W3s[64 * 64];             // 16 KB fp32

  // X staging geometry: call c covers rows c*32..c*32+31; thread row = c*32 + (t>>3)
  const int xr   = t >> 3;                        // 0..31
  const int xkey = ((t & 7) ^ (xr & 7)) << 3;     // pre-swizzled k-elem offset (same all c)
  const unsigned short* xp[4];
#pragma unroll
  for (int c = 0; c < 4; ++c) {
    int row = min(mt * 128 + c * 32 + xr, n - 1);
    xp[c] = xbf + (size_t)tok[e * NTOK + row] * HIDDEN + xkey;
  }

  // W staging geometry: call c covers rows c*16..c*16+15; thread row = c*16 + (t>>4)
  const int wr   = t >> 4;                        // 0..15
  const int wkey = ((t & 15) ^ wr) << 2;          // pre-swizzled fp32-elem offset
  const float* w1p = w1f + (size_t)e * FFN_DIM * HIDDEN + ((size_t)nt * 64 + wr) * HIDDEN + wkey;
  const float* w3p = w3f + (size_t)e * FFN_DIM * HIDDEN + ((size_t)nt * 64 + wr) * HIDDEN + wkey;

  f32x4 acc1[4][2], acc3[4][2];
#pragma unroll
  for (int i = 0; i < 4; ++i)
#pragma unroll
    for (int j = 0; j < 2; ++j) { acc1[i][j] = (f32x4)0.f; acc3[i][j] = (f32x4)0.f; }

  const int Moff = (w & 1) * 64;        // 2 waves over M=128
  const int Noff = (w >> 1) * 32;       // 2 waves over N=64
  const int lr = l & 15;
  const int lg = l >> 4;

  for (int kb = 0; kb < HIDDEN / 64; ++kb) {
    __syncthreads();                    // previous compute done with LDS
    const int ko = kb * 64;
#pragma unroll
    for (int c = 0; c < 4; ++c)
      ld_g2l16(xp[c] + ko, (char*)Xs + c * 4096 + w * 1024);
#pragma unroll
    for (int c = 0; c < 4; ++c) {
      ld_g2l16(w1p + (size_t)c * 16 * HIDDEN + ko, (char*)W1s + c * 4096 + w * 1024);
      ld_g2l16(w3p + (size_t)c * 16 * HIDDEN + ko, (char*)W3s + c * 4096 + w * 1024);
    }
    __syncthreads();                    // drains vmcnt -> LDS ready
#pragma unroll
    for (int s = 0; s < 2; ++s) {
      const int ub = 4 * s + lg;        // A bf16 unit; B fp32 unit pair {2ub, 2ub+1}
      bf16x8 a[4];
#pragma unroll
      for (int mi = 0; mi < 4; ++mi) {
        const int R = Moff + mi * 16 + lr;
        a[mi] = *(const bf16x8*)((const char*)Xs + R * 128 + ((ub ^ (R & 7)) << 4));
      }
#pragma unroll
      for (int ni = 0; ni < 2; ++ni) {
        const int R  = Noff + ni * 16 + lr;
        const int p0 = (2 * ub) ^ (R & 15);     // phys unit holding low half
        float4 lo1 = *(const float4*)((const char*)W1s + R * 256 + (p0 << 4));
        float4 hi1 = *(const float4*)((const char*)W1s + R * 256 + ((p0 ^ 1) << 4));
        float4 lo3 = *(const float4*)((const char*)W3s + R * 256 + (p0 << 4));
        float4 hi3 = *(const float4*)((const char*)W3s + R * 256 + ((p0 ^ 1) << 4));
        bf16x8 b1 = cvt8b(lo1, hi1);
        bf16x8 b3 = cvt8b(lo3, hi3);
#pragma unroll
        for (int mi = 0; mi < 4; ++mi) {
          acc1[mi][ni] = __builtin_amdgcn_mfma_f32_16x16x32_bf16(a[mi], b1, acc1[mi][ni], 0, 0, 0);
          acc3[mi][ni] = __builtin_amdgcn_mfma_f32_16x16x32_bf16(a[mi], b3, acc3[mi][ni], 0, 0, 0);
        }
      }
    }
  }

  const size_t rbase = (size_t)base[e] + (size_t)mt * 128;
#pragma unroll
  for (int mi = 0; mi < 4; ++mi)
#pragma unroll
    for (int ni = 0; ni < 2; ++ni)
#pragma unroll
      for (int j = 0; j < 4; ++j) {
        int row = Moff + mi * 16 + lg * 4 + j;
        int col = nt * 64 + Noff + ni * 16 + lr;
        float s1 = acc1[mi][ni][j], s3 = acc3[mi][ni][j];
        float h = (s1 / (1.f + __expf(-s1))) * s3;      // silu(s1)*s3
        H[(rbase + row) * FFN_DIM + col] = f2bf(h);
      }
}

// ---------------- GEMM2: Y = H W2^T, M=128 x N=64 x BK=64, split-K x2, same structure ----------
__global__ __launch_bounds__(256, 4) void gemm2_kernel(
    const unsigned short* __restrict__ H,
    const float* __restrict__ w2f,            // [E][HIDDEN][FFN] fp32
    const int* __restrict__ cnt, const int* __restrict__ base,
    const int* __restrict__ tok, const float* __restrict__ wgt,
    float* __restrict__ out)
{
  const int bid  = blockIdx.x;
  const int e    = bid & 7;
  const int slot = bid >> 3;            // 0..511
  const int mt   = slot & 15;           // 128-row token tile
  const int nt   = (slot >> 4) & 15;    // 64-col hidden tile
  const int sk   = slot >> 8;           // split-K 0..1
  const int n = cnt[e];
  if (mt * 128 >= n) return;
  const int t = threadIdx.x;
  const int w = t >> 6, l = t & 63;

  __shared__ unsigned short Hs[128 * 64];    // 16 KB bf16
  __shared__ float W2s[64 * 64];             // 16 KB fp32
  __shared__ int   stok[128];
  __shared__ float swgt[128];

  if (t < 128) {
    int idx = mt * 128 + t;
    int ok = idx < n;
    stok[t] = ok ? tok[e * NTOK + idx] : -1;
    swgt[t] = ok ? wgt[e * NTOK + idx] : 0.f;
  }

  const int xr   = t >> 3;
  const int xkey = ((t & 7) ^ (xr & 7)) << 3;
  const unsigned short* Hp = H + (size_t)(base[e] + mt * 128 + xr) * FFN_DIM
                               + sk * (FFN_DIM / 2) + xkey;
  const int wr   = t >> 4;
  const int wkey = ((t & 15) ^ wr) << 2;
  const float* w2p = w2f + (size_t)e * HIDDEN * FFN_DIM + ((size_t)nt * 64 + wr) * FFN_DIM
                        + sk * (FFN_DIM / 2) + wkey;

  f32x4 acc[4][2];
#pragma unroll
  for (int i = 0; i < 4; ++i)
#pragma unroll
    for (int j = 0; j < 2; ++j) acc[i][j] = (f32x4)0.f;

  const int Moff = (w & 1) * 64;
  const int Noff = (w >> 1) * 32;
  const int lr = l & 15;
  const int lg = l >> 4;

  for (int kb = 0; kb < FFN_DIM / 2 / 64; ++kb) {
    __syncthreads();
    const int ko = kb * 64;
#pragma unroll
    for (int c = 0; c < 4; ++c)
      ld_g2l16(Hp + (size_t)c * 32 * FFN_DIM + ko, (char*)Hs + c * 4096 + w * 1024);
#pragma unroll
    for (int c = 0; c < 4; ++c)
      ld_g2l16(w2p + (size_t)c * 16 * FFN_DIM + ko, (char*)W2s + c * 4096 + w * 1024);
    __syncthreads();
#pragma unroll
    for (int s = 0; s < 2; ++s) {
      const int ub = 4 * s + lg;
      bf16x8 a[4];
#pragma unroll
      for (int mi = 0; mi < 4; ++mi) {
        const int R = Moff + mi * 16 + lr;
        a[mi] = *(const bf16x8*)((const char*)Hs + R * 128 + ((ub ^ (R & 7)) << 4));
      }
#pragma unroll
      for (int ni = 0; ni < 2; ++ni) {
        const int R  = Noff + ni * 16 + lr;
        const int p0 = (2 * ub) ^ (R & 15);
        float4 lo = *(const float4*)((const char*)W2s + R * 256 + (p0 << 4));
        float4 hi = *(const float4*)((const char*)W2s + R * 256 + ((p0 ^ 1) << 4));
        bf16x8 b = cvt8b(lo, hi);
#pragma unroll
        for (int mi = 0; mi < 4; ++mi)
          acc[mi][ni] = __builtin_amdgcn_mfma_f32_16x16x32_bf16(a[mi], b, acc[mi][ni], 0, 0, 0);
      }
    }
  }

#pragma unroll
  for (int mi = 0; mi < 4; ++mi)
#pragma unroll
    for (int ni = 0; ni < 2; ++ni)
#pragma unroll
      for (int j = 0; j < 4; ++j) {
        int row = Moff + mi * 16 + lg * 4 + j;
        int tk = stok[row];
        if (tk >= 0) {
          int col = nt * 64 + Noff + ni * 16 + lr;
          atomicAdd(&out[(size_t)tk * HIDDEN + col], swgt[row] * acc[mi][ni][j]);
        }
      }
}

// ================= fp32 fallback path (used only if ws too small) =================
#define TT 12
#define FC 256
#define NCHUNK (FFN_DIM / FC)

__global__ __launch_bounds__(256) void moe_ffn_kernel(
    const float* __restrict__ x,
    const float* __restrict__ w1, const float* __restrict__ w2,
    const float* __restrict__ w3,
    const int* __restrict__ cnt, const int* __restrict__ tok,
    const float* __restrict__ wgt, float* __restrict__ out)
{
  const int e  = blockIdx.y;
  const int n  = cnt[e];
  const int ts = blockIdx.x * TT;
  if (ts >= n) return;
  const int tid = threadIdx.x;

  __shared__ float xs[TT * HIDDEN];
  __shared__ float hc[TT * FC];
  __shared__ int   stok[TT];
  __shared__ float swgt[TT];

  if (tid < TT) {
    int idx = ts + tid;
    int tk  = (idx < n) ? tok[e * NTOK + idx] : -1;
    stok[tid] = tk;
    swgt[tid] = (idx < n) ? wgt[e * NTOK + idx] : 0.f;
  }
  __syncthreads();
#pragma unroll
  for (int i = 0; i < TT; ++i) {
    int tk = stok[i];
    float4 v = make_float4(0.f, 0.f, 0.f, 0.f);
    if (tk >= 0) v = ((const float4*)(x + (size_t)tk * HIDDEN))[tid];
    ((float4*)(xs + i * HIDDEN))[tid] = v;
  }
  __syncthreads();

  const float* w1e = w1 + (size_t)e * FFN_DIM * HIDDEN;
  const float* w3e = w3 + (size_t)e * FFN_DIM * HIDDEN;
  const float* w2e = w2 + (size_t)e * HIDDEN * FFN_DIM;

  float yacc[4][TT];
#pragma unroll
  for (int j = 0; j < 4; ++j)
#pragma unroll
    for (int t = 0; t < TT; ++t) yacc[j][t] = 0.f;

  for (int c = 0; c < NCHUNK; ++c) {
    const int f = c * FC + tid;
    const float4* r1 = (const float4*)(w1e + (size_t)f * HIDDEN);
    const float4* r3 = (const float4*)(w3e + (size_t)f * HIDDEN);
    float a1[TT], a3[TT];
#pragma unroll
    for (int t = 0; t < TT; ++t) { a1[t] = 0.f; a3[t] = 0.f; }
    for (int k = 0; k < HIDDEN / 4; ++k) {
      float4 v1 = r1[k];
      float4 v3 = r3[k];
#pragma unroll
      for (int t = 0; t < TT; ++t) {
        float4 xv = *(const float4*)(xs + t * HIDDEN + 4 * k);
        a1[t] += xv.x * v1.x + xv.y * v1.y + xv.z * v1.z + xv.w * v1.w;
        a3[t] += xv.x * v3.x + xv.y * v3.y + xv.z * v3.z + xv.w * v3.w;
      }
    }
    __syncthreads();
#pragma unroll
    for (int t = 0; t < TT; ++t) {
      float g  = a1[t];
      float sg = g / (1.f + __expf(-g));
      hc[t * FC + tid] = sg * a3[t];
    }
    __syncthreads();
    const float4* r20 = (const float4*)(w2e + (size_t)(tid      ) * FFN_DIM + c * FC);
    const float4* r21 = (const float4*)(w2e + (size_t)(tid + 256) * FFN_DIM + c * FC);
    const float4* r22 = (const float4*)(w2e + (size_t)(tid + 512) * FFN_DIM + c * FC);
    const float4* r23 = (const float4*)(w2e + (size_t)(tid + 768) * FFN_DIM + c * FC);
    for (int k = 0; k < FC / 4; ++k) {
      float4 wv0 = r20[k], wv1 = r21[k], wv2 = r22[k], wv3 = r23[k];
#pragma unroll
      for (int t = 0; t < TT; ++t) {
        float4 hv = *(const float4*)(hc + t * FC + 4 * k);
        yacc[0][t] += hv.x * wv0.x + hv.y * wv0.y + hv.z * wv0.z + hv.w * wv0.w;
        yacc[1][t] += hv.x * wv1.x + hv.y * wv1.y + hv.z * wv1.z + hv.w * wv1.w;
        yacc[2][t] += hv.x * wv2.x + hv.y * wv2.y + hv.z * wv2.z + hv.w * wv2.w;
        yacc[3][t] += hv.x * wv3.x + hv.y * wv3.y + hv.z * wv3.z + hv.w * wv3.w;
      }
    }
  }

#pragma unroll
  for (int t = 0; t < TT; ++t) {
    int tk = stok[t];
    if (tk < 0) continue;
    float wt = swgt[t];
    float* orow = out + (size_t)tk * HIDDEN;
    atomicAdd(orow + tid,       wt * yacc[0][t]);
    atomicAdd(orow + tid + 256, wt * yacc[1][t]);
    atomicAdd(orow + tid + 512, wt * yacc[2][t]);
    atomicAdd(orow + tid + 768, wt * yacc[3][t]);
  }
}

extern "C" void kernel_launch(void* const* d_in, const int* in_sizes, int n_in,
                              void* d_out, int out_size, void* d_ws, size_t ws_size,
                              hipStream_t stream) {
  const float* x  = (const float*)d_in[0];
  const float* gw = (const float*)d_in[1];
  const float* w1 = (const float*)d_in[2];
  const float* w2 = (const float*)d_in[3];
  const float* w3 = (const float*)d_in[4];
  float* out    = (float*)d_out;
  float* logits = out + (size_t)NTOK * HIDDEN;

  char* ws = (char*)d_ws;
  int*   cnt  = (int*)(ws + OFF_CNT);
  int*   base = (int*)(ws + OFF_BASE);
  int*   tokp = (int*)(ws + OFF_TOK);
  float* wgtp = (float*)(ws + OFF_WGT);

  const bool big = (ws_size >= WS_NEED);
  unsigned short* xbf  = big ? (unsigned short*)(ws + OFF_XBF) : (unsigned short*)0;
  unsigned short* Hbuf = big ? (unsigned short*)(ws + OFF_H)   : (unsigned short*)0;

  hipMemsetAsync(out, 0, (size_t)NTOK * HIDDEN * sizeof(float), stream);
  hipMemsetAsync(cnt, 0, NEXP * sizeof(int), stream);

  router_kernel<<<NTOK, 256, 0, stream>>>(x, gw, logits, cnt, tokp, wgtp, xbf);

  if (big) {
    prefix_kernel<<<1, 64, 0, stream>>>(cnt, base);
    gemm1_kernel<<<NEXP * 16 * 32, 256, 0, stream>>>(xbf, w1, w3, cnt, base, tokp, Hbuf);
    gemm2_kernel<<<NEXP * 16 * 16 * 2, 256, 0, stream>>>(Hbuf, w2, cnt, base, tokp, wgtp, out);
  } else {
    dim3 grid((NTOK + TT - 1) / TT, NEXP);
    moe_ffn_kernel<<<grid, 256, 0, stream>>>(x, w1, w2, w3, cnt, tokp, wgtp, out);
  }
}